// Round 3
// baseline (587.779 us; speedup 1.0000x reference)
//
#include <hip/hip_runtime.h>
#include <hip/hip_bf16.h>
#include <math.h>

typedef __bf16 bf16x8 __attribute__((ext_vector_type(8)));
typedef __bf16 bf16x4 __attribute__((ext_vector_type(4)));
typedef float f32x4 __attribute__((ext_vector_type(4)));

static __device__ __forceinline__ f32x4 mfma16(bf16x8 a, bf16x8 b, f32x4 c) {
  return __builtin_amdgcn_mfma_f32_16x16x32_bf16(a, b, c, 0, 0, 0);
}

// ---------------- ws byte layout (unchanged from R1) ----------------
// 0      : wq_pk  [kt4][dt8][lane64][8] bf16  (scale folded)   32768 B
// 32768  : wk_pk  [kt4][dt8][lane64][8] bf16                   32768 B
// 65536  : wv_pk  [kt4][dt8][lane64][8] bf16                   32768 B
// 98304  : f1_pk  [kt4][ht2][lane64][8] bf16 (fc1^T A-frags)    8192 B
// 106496 : f2_pk  [dt8][lane64][8] bf16 (fc2 B-frags)           8192 B
// 114688 : biasT  [h4][mt4][nt4][lane64] float4                65536 B
// 180224 : bq_s   [128] float (bq*scale)                         512 B

__global__ void wattn_prep(const float* __restrict__ wq, const float* __restrict__ bq,
                           const float* __restrict__ wkv,
                           const float* __restrict__ f1w, const float* __restrict__ f2w,
                           const float* __restrict__ rpb, const int* __restrict__ rel,
                           char* __restrict__ ws)
{
  const int idx = blockIdx.x * 256 + threadIdx.x;
  const float scale = 0.17677669529663687f; // 32^-0.5
  unsigned short* ws16 = (unsigned short*)ws;
  float* wsf = (float*)ws;

  if (idx < 2048) {
    const int lane = idx & 63, dt = (idx >> 6) & 7, kt = idx >> 9;
    const int gg = lane >> 4, cc = lane & 15;
    bf16x8 v;
#pragma unroll
    for (int i = 0; i < 8; ++i)
      v[i] = (__bf16)(wq[(kt * 32 + gg * 8 + i) * 128 + dt * 16 + cc] * scale);
    *(bf16x8*)(ws16 + idx * 8) = v;
  } else if (idx < 4096) {
    const int e = idx - 2048;
    const int lane = e & 63, dt = (e >> 6) & 7, kt = e >> 9;
    const int gg = lane >> 4, cc = lane & 15;
    bf16x8 v;
#pragma unroll
    for (int i = 0; i < 8; ++i)
      v[i] = (__bf16)(wkv[(kt * 32 + gg * 8 + i) * 256 + dt * 16 + cc]);
    *(bf16x8*)(ws16 + 16384 + e * 8) = v;
  } else if (idx < 6144) {
    const int e = idx - 4096;
    const int lane = e & 63, dt = (e >> 6) & 7, kt = e >> 9;
    const int gg = lane >> 4, cc = lane & 15;
    bf16x8 v;
#pragma unroll
    for (int i = 0; i < 8; ++i)
      v[i] = (__bf16)(wkv[(kt * 32 + gg * 8 + i) * 256 + 128 + dt * 16 + cc]);
    *(bf16x8*)(ws16 + 32768 + e * 8) = v;
  } else if (idx < 6656) {
    const int e = idx - 6144;
    const int lane = e & 63, ht = (e >> 6) & 1, kt = e >> 7;
    const int gg = lane >> 4, cc = lane & 15;
    bf16x8 v;
#pragma unroll
    for (int i = 0; i < 8; ++i)
      v[i] = (__bf16)(f1w[(kt * 32 + gg * 8 + i) * 32 + ht * 16 + cc]);
    *(bf16x8*)(ws16 + 49152 + e * 8) = v;
  } else if (idx < 7168) {
    const int e = idx - 6656;
    const int lane = e & 63, dt = e >> 6;
    const int gg = lane >> 4, cc = lane & 15;
    bf16x8 v;
#pragma unroll
    for (int i = 0; i < 8; ++i)
      v[i] = (__bf16)(f2w[(gg * 8 + i) * 128 + dt * 16 + cc]);
    *(bf16x8*)(ws16 + 53248 + e * 8) = v;
  } else if (idx < 11264) {
    const int e = idx - 7168;
    const int lane = e & 63, nt = (e >> 6) & 3, mt = (e >> 8) & 3, h = e >> 10;
    const int gg = lane >> 4, cc = lane & 15;
    const int q = nt * 16 + cc;
    f32x4 v;
#pragma unroll
    for (int r = 0; r < 4; ++r) {
      const int key = mt * 16 + gg * 4 + r;
      v[r] = rpb[rel[q * 64 + key] * 4 + h];
    }
    *(f32x4*)(wsf + 28672 + e * 4) = v;
  } else if (idx < 11392) {
    const int d = idx - 11264;
    wsf[45056 + d] = bq[d] * scale;
  }
}

// Per-wave private LDS scratch (12 KB/wave, 48 KB total), phase-aliased:
//  wave base WB = w*12288
//  [WB+0,     WB+4096)  : Q  [q/2][(q&1)*32+dloc] bf16  -> P (8KB spans Q+K) -> H (1KB)
//  [WB+4096,  WB+8192)  : K  [key/2][(key&1)*32+dloc] bf16
//  [WB+8192,  WB+12288) : V^T [dloc][t] bf16            -> O [q/2][(q&1)*32+dloc]
// All offsets XOR-swizzled on byte bits [4:6] -> <=2-way conflicts everywhere.
// ONE __syncthreads per block (before MLP, the only cross-wave exchange: O).
__global__ __launch_bounds__(256, 3) void wattn_main(
    const float* __restrict__ x,
    const float* __restrict__ bkv,
    const float* __restrict__ f1b,
    const float* __restrict__ f2b,
    const char* __restrict__ ws,
    float* __restrict__ out)
{
  extern __shared__ char smem[];
  const int tid = threadIdx.x;
  const int w = tid >> 6;        // wave id == head id
  const int l = tid & 63;
  const int g = l >> 4;
  const int c = l & 15;
  const size_t b = blockIdx.x;
  const int WB = w * 12288;
  const int QB = WB, KB = WB + 4096, VB = WB + 8192;
  const int PB = WB, OB = WB + 8192, HB = WB;

  const unsigned short* ws16 = (const unsigned short*)ws;
  const bf16x8* wqp = (const bf16x8*)(ws16);
  const bf16x8* wkp = (const bf16x8*)(ws16 + 16384);
  const bf16x8* wvp = (const bf16x8*)(ws16 + 32768);
  const bf16x8* f1p = (const bf16x8*)(ws16 + 49152);
  const bf16x8* f2p = (const bf16x8*)(ws16 + 53248);
  const f32x4* biasp = (const f32x4*)(ws16 + 57344);
  const float* bqs = (const float*)(ws16 + 90112);

  // ---- x fragments for ALL 64 tokens, direct global->reg (L2 merges the
  // 4 waves' duplicate lines). B-frag AND A-frag layout simultaneously.
  bf16x8 xf[4][4];
  {
    const float* xg = x + b * 8192;
#pragma unroll
    for (int tt = 0; tt < 4; ++tt)
#pragma unroll
      for (int kt = 0; kt < 4; ++kt) {
        const float* p = xg + (tt * 16 + c) * 128 + kt * 32 + g * 8;
        f32x4 u = *(const f32x4*)p;
        f32x4 v = *(const f32x4*)(p + 4);
        bf16x8 f = { (__bf16)u[0], (__bf16)u[1], (__bf16)u[2], (__bf16)u[3],
                     (__bf16)v[0], (__bf16)v[1], (__bf16)v[2], (__bf16)v[3] };
        xf[tt][kt] = f;
      }
  }

  // ---- projections for this wave's head slice d in [32w, 32w+32)
#pragma unroll
  for (int dt = 0; dt < 2; ++dt) {
    const int dtg = 2 * w + dt;
    {
      // Q^T[dloc][t], K^T[dloc][t] (swapped orientation)
      f32x4 qa[4], kk[4];
      const f32x4 bq4 = *(const f32x4*)(bqs + dtg * 16 + g * 4);
      const f32x4 bk4 = *(const f32x4*)(bkv + dtg * 16 + g * 4);
#pragma unroll
      for (int tt = 0; tt < 4; ++tt) { qa[tt] = bq4; kk[tt] = bk4; }
#pragma unroll
      for (int kt = 0; kt < 4; ++kt) {
        const bf16x8 wfq = wqp[(kt * 8 + dtg) * 64 + l];
        const bf16x8 wfk = wkp[(kt * 8 + dtg) * 64 + l];
#pragma unroll
        for (int tt = 0; tt < 4; ++tt) {
          qa[tt] = mfma16(wfq, xf[tt][kt], qa[tt]);
          kk[tt] = mfma16(wfk, xf[tt][kt], kk[tt]);
        }
      }
#pragma unroll
      for (int tt = 0; tt < 4; ++tt) {
        const int q = tt * 16 + c;   // token
        const int off = (((q >> 1) * 128 + (q & 1) * 64 + (dt * 16 + g * 4) * 2)) ^ (((q >> 1) & 7) << 4);
        bf16x4 q4 = { (__bf16)qa[tt][0], (__bf16)qa[tt][1], (__bf16)qa[tt][2], (__bf16)qa[tt][3] };
        bf16x4 k4 = { (__bf16)kk[tt][0], (__bf16)kk[tt][1], (__bf16)kk[tt][2], (__bf16)kk[tt][3] };
        *(bf16x4*)(smem + QB + off) = q4;
        *(bf16x4*)(smem + KB + off) = k4;
      }
    }
    {
      // V direct orientation D[t][dloc]; b64 writes along t into V^T[dloc][t]
      const float bv = bkv[128 + dtg * 16 + c];
      f32x4 va4[4];
#pragma unroll
      for (int tt = 0; tt < 4; ++tt) va4[tt] = (f32x4){ bv, bv, bv, bv };
#pragma unroll
      for (int kt = 0; kt < 4; ++kt) {
        const bf16x8 wf = wvp[(kt * 8 + dtg) * 64 + l];
#pragma unroll
        for (int tt = 0; tt < 4; ++tt)
          va4[tt] = mfma16(xf[tt][kt], wf, va4[tt]);
      }
#pragma unroll
      for (int tt = 0; tt < 4; ++tt) {
        const int dloc = dt * 16 + c;
        const int off = ((dloc * 128 + (tt * 16 + g * 4) * 2)) ^ ((dloc & 7) << 4);
        bf16x4 v4 = { (__bf16)va4[tt][0], (__bf16)va4[tt][1], (__bf16)va4[tt][2], (__bf16)va4[tt][3] };
        *(bf16x4*)(smem + VB + off) = v4;
      }
    }
  }

  // ---- attention (all private to this wave; no barrier)
  bf16x8 ka[4], qb[4];
#pragma unroll
  for (int mt = 0; mt < 4; ++mt) {
    const int key = mt * 16 + c;
    const int off = (((key >> 1) * 128 + (key & 1) * 64 + g * 16)) ^ (((key >> 1) & 7) << 4);
    ka[mt] = *(const bf16x8*)(smem + KB + off);
  }
#pragma unroll
  for (int nt = 0; nt < 4; ++nt) {
    const int q = nt * 16 + c;
    const int off = (((q >> 1) * 128 + (q & 1) * 64 + g * 16)) ^ (((q >> 1) & 7) << 4);
    qb[nt] = *(const bf16x8*)(smem + QB + off);
  }
  f32x4 s[4][4];
#pragma unroll
  for (int mt = 0; mt < 4; ++mt)
#pragma unroll
    for (int nt = 0; nt < 4; ++nt)
      s[mt][nt] = mfma16(ka[mt], qb[nt], biasp[((w * 4 + mt) * 4 + nt) * 64 + l]);

  // softmax over keys (per-lane 16 + butterfly over g)
  float rinv[4];
#pragma unroll
  for (int nt = 0; nt < 4; ++nt) {
    float m = s[0][nt][0];
#pragma unroll
    for (int mt = 0; mt < 4; ++mt)
#pragma unroll
      for (int r = 0; r < 4; ++r)
        m = fmaxf(m, s[mt][nt][r]);
    m = fmaxf(m, __shfl_xor(m, 16, 64));
    m = fmaxf(m, __shfl_xor(m, 32, 64));
    float sum = 0.f;
#pragma unroll
    for (int mt = 0; mt < 4; ++mt)
#pragma unroll
      for (int r = 0; r < 4; ++r) {
        const float e = __expf(s[mt][nt][r] - m);
        s[mt][nt][r] = e;
        sum += e;
      }
    sum += __shfl_xor(sum, 16, 64);
    sum += __shfl_xor(sum, 32, 64);
    rinv[nt] = 1.0f / sum;
  }

  // P[q][key] bf16 (unnormalized), rows 128B, overwrites Q+K (reads done)
#pragma unroll
  for (int nt = 0; nt < 4; ++nt) {
    const int q = nt * 16 + c;
#pragma unroll
    for (int mt = 0; mt < 4; ++mt) {
      const int off = ((q * 128 + (mt * 16 + g * 4) * 2)) ^ ((q & 7) << 4);
      bf16x4 p4 = { (__bf16)s[mt][nt][0], (__bf16)s[mt][nt][1],
                    (__bf16)s[mt][nt][2], (__bf16)s[mt][nt][3] };
      *(bf16x4*)(smem + PB + off) = p4;
    }
  }

  // PV: O^T[dloc][q] = sum_key V^T[dloc][key] * P^T[key][q]
  bf16x8 va[2][2], pbf[2][4];
#pragma unroll
  for (int dt2 = 0; dt2 < 2; ++dt2)
#pragma unroll
    for (int ks = 0; ks < 2; ++ks) {
      const int dloc = dt2 * 16 + c;
      const int off = ((dloc * 128 + ks * 64 + g * 16)) ^ ((dloc & 7) << 4);
      va[dt2][ks] = *(const bf16x8*)(smem + VB + off);
    }
#pragma unroll
  for (int ks = 0; ks < 2; ++ks)
#pragma unroll
    for (int nt = 0; nt < 4; ++nt) {
      const int q = nt * 16 + c;
      const int off = ((q * 128 + ks * 64 + g * 16)) ^ ((q & 7) << 4);
      pbf[ks][nt] = *(const bf16x8*)(smem + PB + off);
    }
#pragma unroll
  for (int nt = 0; nt < 4; ++nt) {
    const float rv = rinv[nt];
    const int q = nt * 16 + c;
#pragma unroll
    for (int dt2 = 0; dt2 < 2; ++dt2) {
      f32x4 acc = { 0.f, 0.f, 0.f, 0.f };
      acc = mfma16(va[dt2][0], pbf[0][nt], acc);
      acc = mfma16(va[dt2][1], pbf[1][nt], acc);
      const int off = (((q >> 1) * 128 + (q & 1) * 64 + (dt2 * 16 + g * 4) * 2)) ^ (((q >> 1) & 7) << 4);
      bf16x4 o4 = { (__bf16)(acc[0] * rv), (__bf16)(acc[1] * rv),
                    (__bf16)(acc[2] * rv), (__bf16)(acc[3] * rv) };
      *(bf16x4*)(smem + OB + off) = o4;   // overwrites own V (reads done)
    }
  }

  __syncthreads();   // the ONLY barrier: O slices become cross-wave visible

  // ---- MLP on token tile w
  bf16x8 ob[4];
#pragma unroll
  for (int kt = 0; kt < 4; ++kt) {   // d-chunk kt lives in wave kt's O region
    const int t = w * 16 + c;
    const int off = (((t >> 1) * 128 + (t & 1) * 64 + g * 16)) ^ (((t >> 1) & 7) << 4);
    ob[kt] = *(const bf16x8*)(smem + kt * 12288 + 8192 + off);
  }
  {
    // fc1 swapped: D[h][t]; gelu; H[t][h] paired-row layout (1KB, over P)
#pragma unroll
    for (int ht = 0; ht < 2; ++ht) {
      f32x4 ah = *(const f32x4*)(f1b + ht * 16 + g * 4);
#pragma unroll
      for (int kt = 0; kt < 4; ++kt)
        ah = mfma16(f1p[(kt * 2 + ht) * 64 + l], ob[kt], ah);
      bf16x4 h4;
#pragma unroll
      for (int r = 0; r < 4; ++r) {
        const float v = ah[r];
        h4[r] = (__bf16)(0.5f * v * (1.0f + erff(v * 0.70710678118654752f)));
      }
      const int off = (((c >> 1) * 128 + (c & 1) * 64 + (ht * 16 + g * 4) * 2)) ^ (((c >> 1) & 7) << 4);
      *(bf16x4*)(smem + HB + off) = h4;
    }
  }
  bf16x8 ha;
  {
    const int off = (((c >> 1) * 128 + (c & 1) * 64 + g * 16)) ^ (((c >> 1) & 7) << 4);
    ha = *(const bf16x8*)(smem + HB + off);
  }
  {
    // fc2 direct: D[t][d] + f2b -> global
    float* og = out + b * 8192 + (size_t)(w * 16) * 128;
#pragma unroll
    for (int dt = 0; dt < 8; ++dt) {
      const float bb = f2b[dt * 16 + c];
      f32x4 ay = { bb, bb, bb, bb };
      ay = mfma16(ha, f2p[dt * 64 + l], ay);
#pragma unroll
      for (int r = 0; r < 4; ++r)
        og[(g * 4 + r) * 128 + dt * 16 + c] = ay[r];
    }
  }
}

extern "C" void kernel_launch(void* const* d_in, const int* in_sizes, int n_in,
                              void* d_out, int out_size, void* d_ws, size_t ws_size,
                              hipStream_t stream) {
  const float* x    = (const float*)d_in[0];
  const float* rpb  = (const float*)d_in[1];
  const float* wq   = (const float*)d_in[2];
  const float* bq   = (const float*)d_in[3];
  const float* wkv  = (const float*)d_in[4];
  const float* bkv  = (const float*)d_in[5];
  const float* f1w  = (const float*)d_in[6];
  const float* f1b  = (const float*)d_in[7];
  const float* f2w  = (const float*)d_in[8];
  const float* f2b  = (const float*)d_in[9];
  const int*   rel  = (const int*)d_in[10];
  float* out = (float*)d_out;
  char* ws = (char*)d_ws;
  if (ws_size < 180736) return;

  const int nB = in_sizes[0] / 8192;   // 16384 windows

  wattn_prep<<<45, 256, 0, stream>>>(wq, bq, wkv, f1w, f2w, rpb, rel, ws);
  wattn_main<<<nB, 256, 49152, stream>>>(x, bkv, f1b, f2b, ws, out);
}

// Round 4
// 587.165 us; speedup vs baseline: 1.0010x; 1.0010x over previous
//
#include <hip/hip_runtime.h>
#include <hip/hip_bf16.h>
#include <math.h>

typedef __bf16 bf16x8 __attribute__((ext_vector_type(8)));
typedef __bf16 bf16x4 __attribute__((ext_vector_type(4)));
typedef float f32x4 __attribute__((ext_vector_type(4)));

static __device__ __forceinline__ f32x4 mfma16(bf16x8 a, bf16x8 b, f32x4 c) {
  return __builtin_amdgcn_mfma_f32_16x16x32_bf16(a, b, c, 0, 0, 0);
}

static __device__ __forceinline__ int pk2(float lo, float hi) {
  union { __bf16 h[2]; int i; } u;
  u.h[0] = (__bf16)lo; u.h[1] = (__bf16)hi;
  return u.i;
}

// C-frag-pair -> A/B-frag transform, fully in-register.
// Input: two stacked 16x16 C-frag tiles T0 (rows 0-15), T1 (rows 16-31) of a
// 32x16 matrix M, as bf16 pairs: t?a = pk(r0,r1) [rows g*4+0,1],
// t?b = pk(r2,r3) [rows g*4+2,3] at lane (g,c) = col c.
// Output: lane(g,c) holds M[g*8+i][c], i=0..7 (A/B-frag for K=32 MFMA).
// dword j <- reg (j&1 ? b : a) of tile (g<2 ? T0 : T1) at lane (2*(g&1)+(j>>1))*16+c.
static __device__ __forceinline__ bf16x8 xform(int aA, int aB, bool lo,
                                               int t0a, int t0b, int t1a, int t1b) {
  union { int d[4]; bf16x8 v; } r;
  int x0 = __builtin_amdgcn_ds_bpermute(aA, t0a);
  int y0 = __builtin_amdgcn_ds_bpermute(aA, t1a);
  int x1 = __builtin_amdgcn_ds_bpermute(aA, t0b);
  int y1 = __builtin_amdgcn_ds_bpermute(aA, t1b);
  int x2 = __builtin_amdgcn_ds_bpermute(aB, t0a);
  int y2 = __builtin_amdgcn_ds_bpermute(aB, t1a);
  int x3 = __builtin_amdgcn_ds_bpermute(aB, t0b);
  int y3 = __builtin_amdgcn_ds_bpermute(aB, t1b);
  r.d[0] = lo ? x0 : y0;
  r.d[1] = lo ? x1 : y1;
  r.d[2] = lo ? x2 : y2;
  r.d[3] = lo ? x3 : y3;
  return r.v;
}

// ---------------- ws byte layout (unchanged) ----------------
// 0      : wq_pk  [kt4][dt8][lane64][8] bf16  (scale folded)   32768 B
// 32768  : wk_pk  [kt4][dt8][lane64][8] bf16                   32768 B
// 65536  : wv_pk  [kt4][dt8][lane64][8] bf16                   32768 B
// 98304  : f1_pk  [kt4][ht2][lane64][8] bf16 (fc1^T A-frags)    8192 B
// 106496 : f2_pk  [dt8][lane64][8] bf16 (fc2 B-frags)           8192 B
// 114688 : biasT  [h4][mt4][nt4][lane64] float4                65536 B
// 180224 : bq_s   [128] float (bq*scale)                         512 B

__global__ void wattn_prep(const float* __restrict__ wq, const float* __restrict__ bq,
                           const float* __restrict__ wkv,
                           const float* __restrict__ f1w, const float* __restrict__ f2w,
                           const float* __restrict__ rpb, const int* __restrict__ rel,
                           char* __restrict__ ws)
{
  const int idx = blockIdx.x * 256 + threadIdx.x;
  const float scale = 0.17677669529663687f; // 32^-0.5
  unsigned short* ws16 = (unsigned short*)ws;
  float* wsf = (float*)ws;

  if (idx < 2048) {
    const int lane = idx & 63, dt = (idx >> 6) & 7, kt = idx >> 9;
    const int gg = lane >> 4, cc = lane & 15;
    bf16x8 v;
#pragma unroll
    for (int i = 0; i < 8; ++i)
      v[i] = (__bf16)(wq[(kt * 32 + gg * 8 + i) * 128 + dt * 16 + cc] * scale);
    *(bf16x8*)(ws16 + idx * 8) = v;
  } else if (idx < 4096) {
    const int e = idx - 2048;
    const int lane = e & 63, dt = (e >> 6) & 7, kt = e >> 9;
    const int gg = lane >> 4, cc = lane & 15;
    bf16x8 v;
#pragma unroll
    for (int i = 0; i < 8; ++i)
      v[i] = (__bf16)(wkv[(kt * 32 + gg * 8 + i) * 256 + dt * 16 + cc]);
    *(bf16x8*)(ws16 + 16384 + e * 8) = v;
  } else if (idx < 6144) {
    const int e = idx - 4096;
    const int lane = e & 63, dt = (e >> 6) & 7, kt = e >> 9;
    const int gg = lane >> 4, cc = lane & 15;
    bf16x8 v;
#pragma unroll
    for (int i = 0; i < 8; ++i)
      v[i] = (__bf16)(wkv[(kt * 32 + gg * 8 + i) * 256 + 128 + dt * 16 + cc]);
    *(bf16x8*)(ws16 + 32768 + e * 8) = v;
  } else if (idx < 6656) {
    const int e = idx - 6144;
    const int lane = e & 63, ht = (e >> 6) & 1, kt = e >> 7;
    const int gg = lane >> 4, cc = lane & 15;
    bf16x8 v;
#pragma unroll
    for (int i = 0; i < 8; ++i)
      v[i] = (__bf16)(f1w[(kt * 32 + gg * 8 + i) * 32 + ht * 16 + cc]);
    *(bf16x8*)(ws16 + 49152 + e * 8) = v;
  } else if (idx < 7168) {
    const int e = idx - 6656;
    const int lane = e & 63, dt = e >> 6;
    const int gg = lane >> 4, cc = lane & 15;
    bf16x8 v;
#pragma unroll
    for (int i = 0; i < 8; ++i)
      v[i] = (__bf16)(f2w[(gg * 8 + i) * 128 + dt * 16 + cc]);
    *(bf16x8*)(ws16 + 53248 + e * 8) = v;
  } else if (idx < 11264) {
    const int e = idx - 7168;
    const int lane = e & 63, nt = (e >> 6) & 3, mt = (e >> 8) & 3, h = e >> 10;
    const int gg = lane >> 4, cc = lane & 15;
    const int q = nt * 16 + cc;
    f32x4 v;
#pragma unroll
    for (int r = 0; r < 4; ++r) {
      const int key = mt * 16 + gg * 4 + r;
      v[r] = rpb[rel[q * 64 + key] * 4 + h];
    }
    *(f32x4*)(wsf + 28672 + e * 4) = v;
  } else if (idx < 11392) {
    const int d = idx - 11264;
    wsf[45056 + d] = bq[d] * scale;
  }
}

// LDS: ONLY the cross-wave O exchange: O[64 tok][128 d] bf16, rows 256 B,
// XOR-swizzled by ((t&7)<<4). 16 KB/block. One barrier.
// All Q/K/V/P/H layout transposes are in-register (xform above).
__global__ __launch_bounds__(256, 4) void wattn_main(
    const float* __restrict__ x,
    const float* __restrict__ bkv,
    const float* __restrict__ f1b,
    const float* __restrict__ f2b,
    const char* __restrict__ ws,
    float* __restrict__ out)
{
  __shared__ __align__(16) char smem[16384];
  const int tid = threadIdx.x;
  const int w = tid >> 6;        // wave id == head id
  const int l = tid & 63;
  const int g = l >> 4;
  const int c = l & 15;
  const size_t b = blockIdx.x;
  const int aA = ((l & 16) << 3) | ((l & 15) << 2);  // byte addr of lane 2*(g&1)*16 + c
  const int aB = aA + 64;                            // lane (2*(g&1)+1)*16 + c
  const bool lolane = (l < 32);

  const unsigned short* ws16 = (const unsigned short*)ws;
  const bf16x8* wqp = (const bf16x8*)(ws16);
  const bf16x8* wkp = (const bf16x8*)(ws16 + 16384);
  const bf16x8* wvp = (const bf16x8*)(ws16 + 32768);
  const bf16x8* f1p = (const bf16x8*)(ws16 + 49152);
  const bf16x8* f2p = (const bf16x8*)(ws16 + 53248);
  const f32x4* biasp = (const f32x4*)(ws16 + 57344);
  const float* bqs = (const float*)(ws16 + 90112);

  // ---- x fragments for all 64 tokens (B-frag layout), direct global->reg
  bf16x8 xf[4][4];
  {
    const float* xg = x + b * 8192;
#pragma unroll
    for (int tt = 0; tt < 4; ++tt)
#pragma unroll
      for (int kt = 0; kt < 4; ++kt) {
        const float* p = xg + (tt * 16 + c) * 128 + kt * 32 + g * 8;
        f32x4 u = *(const f32x4*)p;
        f32x4 v = *(const f32x4*)(p + 4);
        bf16x8 f = { (__bf16)u[0], (__bf16)u[1], (__bf16)u[2], (__bf16)u[3],
                     (__bf16)v[0], (__bf16)v[1], (__bf16)v[2], (__bf16)v[3] };
        xf[tt][kt] = f;
      }
  }

  // ---- Q^T projection (C-frag tiles [dt][tt]) -> bf16 pairs
  int qpA[2][4], qpB[2][4];
#pragma unroll
  for (int dt = 0; dt < 2; ++dt) {
    const int dtg = 2 * w + dt;
    const f32x4 bq4 = *(const f32x4*)(bqs + dtg * 16 + g * 4);
    f32x4 acc[4];
#pragma unroll
    for (int tt = 0; tt < 4; ++tt) acc[tt] = bq4;
#pragma unroll
    for (int kt = 0; kt < 4; ++kt) {
      const bf16x8 wf = wqp[(kt * 8 + dtg) * 64 + l];
#pragma unroll
      for (int tt = 0; tt < 4; ++tt) acc[tt] = mfma16(wf, xf[tt][kt], acc[tt]);
    }
#pragma unroll
    for (int tt = 0; tt < 4; ++tt) {
      qpA[dt][tt] = pk2(acc[tt][0], acc[tt][1]);
      qpB[dt][tt] = pk2(acc[tt][2], acc[tt][3]);
    }
  }
  // ---- K^T projection
  int kpA[2][4], kpB[2][4];
#pragma unroll
  for (int dt = 0; dt < 2; ++dt) {
    const int dtg = 2 * w + dt;
    const f32x4 bk4 = *(const f32x4*)(bkv + dtg * 16 + g * 4);
    f32x4 acc[4];
#pragma unroll
    for (int tt = 0; tt < 4; ++tt) acc[tt] = bk4;
#pragma unroll
    for (int kt = 0; kt < 4; ++kt) {
      const bf16x8 wf = wkp[(kt * 8 + dtg) * 64 + l];
#pragma unroll
      for (int tt = 0; tt < 4; ++tt) acc[tt] = mfma16(wf, xf[tt][kt], acc[tt]);
    }
#pragma unroll
    for (int tt = 0; tt < 4; ++tt) {
      kpA[dt][tt] = pk2(acc[tt][0], acc[tt][1]);
      kpB[dt][tt] = pk2(acc[tt][2], acc[tt][3]);
    }
  }
  // qb[nt]: B-frag of Q^T (M = Q^T[d 0..31][q], T0=dt0, T1=dt1)
  // ka[mt]: A-frag of K rows (M = K^T[d 0..31][key])
  bf16x8 qb[4], ka[4];
#pragma unroll
  for (int t4 = 0; t4 < 4; ++t4) {
    qb[t4] = xform(aA, aB, lolane, qpA[0][t4], qpB[0][t4], qpA[1][t4], qpB[1][t4]);
    ka[t4] = xform(aA, aB, lolane, kpA[0][t4], kpB[0][t4], kpA[1][t4], kpB[1][t4]);
  }

  // ---- V projection (direct: C-frag tiles [tok tt][dloc dt]) -> va A-frags
  int vpA[2][4], vpB[2][4];   // [dt][tt]
#pragma unroll
  for (int dt = 0; dt < 2; ++dt) {
    const int dtg = 2 * w + dt;
    const float bv = bkv[128 + dtg * 16 + c];
    f32x4 acc[4];
#pragma unroll
    for (int tt = 0; tt < 4; ++tt) acc[tt] = (f32x4){ bv, bv, bv, bv };
#pragma unroll
    for (int kt = 0; kt < 4; ++kt) {
      const bf16x8 wf = wvp[(kt * 8 + dtg) * 64 + l];
#pragma unroll
      for (int tt = 0; tt < 4; ++tt) acc[tt] = mfma16(xf[tt][kt], wf, acc[tt]);
    }
#pragma unroll
    for (int tt = 0; tt < 4; ++tt) {
      vpA[dt][tt] = pk2(acc[tt][0], acc[tt][1]);
      vpB[dt][tt] = pk2(acc[tt][2], acc[tt][3]);
    }
  }
  // va[dt2][ks]: A-frag, M = V[tok ks*32..+31][dloc dt2*16..]: T0=tt(2ks), T1=tt(2ks+1)
  bf16x8 va[2][2];
#pragma unroll
  for (int dt2 = 0; dt2 < 2; ++dt2)
#pragma unroll
    for (int ks = 0; ks < 2; ++ks)
      va[dt2][ks] = xform(aA, aB, lolane,
                          vpA[dt2][2 * ks], vpB[dt2][2 * ks],
                          vpA[dt2][2 * ks + 1], vpB[dt2][2 * ks + 1]);

  // ---- attention: S^T = mfma(K, Q) + biasT
  f32x4 s[4][4];
#pragma unroll
  for (int mt = 0; mt < 4; ++mt)
#pragma unroll
    for (int nt = 0; nt < 4; ++nt)
      s[mt][nt] = mfma16(ka[mt], qb[nt], biasp[((w * 4 + mt) * 4 + nt) * 64 + l]);

  // softmax over keys (per-lane 16 + butterfly over g)
  float rinv[4];
#pragma unroll
  for (int nt = 0; nt < 4; ++nt) {
    float m = s[0][nt][0];
#pragma unroll
    for (int mt = 0; mt < 4; ++mt)
#pragma unroll
      for (int r = 0; r < 4; ++r)
        m = fmaxf(m, s[mt][nt][r]);
    m = fmaxf(m, __shfl_xor(m, 16, 64));
    m = fmaxf(m, __shfl_xor(m, 32, 64));
    float sum = 0.f;
#pragma unroll
    for (int mt = 0; mt < 4; ++mt)
#pragma unroll
      for (int r = 0; r < 4; ++r) {
        const float e = __expf(s[mt][nt][r] - m);
        s[mt][nt][r] = e;
        sum += e;
      }
    sum += __shfl_xor(sum, 16, 64);
    sum += __shfl_xor(sum, 32, 64);
    rinv[nt] = 1.0f / sum;
  }

  // P pairs -> pbf[ks][nt]: B-frag, M = S^T[key][q] (T0=mt 2ks, T1=mt 2ks+1)
  int ppA[4][4], ppB[4][4];
#pragma unroll
  for (int mt = 0; mt < 4; ++mt)
#pragma unroll
    for (int nt = 0; nt < 4; ++nt) {
      ppA[mt][nt] = pk2(s[mt][nt][0], s[mt][nt][1]);
      ppB[mt][nt] = pk2(s[mt][nt][2], s[mt][nt][3]);
    }
  bf16x8 pbf[2][4];
#pragma unroll
  for (int ks = 0; ks < 2; ++ks)
#pragma unroll
    for (int nt = 0; nt < 4; ++nt)
      pbf[ks][nt] = xform(aA, aB, lolane,
                          ppA[2 * ks][nt], ppB[2 * ks][nt],
                          ppA[2 * ks + 1][nt], ppB[2 * ks + 1][nt]);

  // ---- PV: O^T[dloc][q] = sum_ks mfma(va, pbf); write O[q][d] to shared LDS
#pragma unroll
  for (int nt = 0; nt < 4; ++nt) {
    const float rv = rinv[nt];
    const int q = nt * 16 + c;
#pragma unroll
    for (int dt2 = 0; dt2 < 2; ++dt2) {
      f32x4 acc = { 0.f, 0.f, 0.f, 0.f };
      acc = mfma16(va[dt2][0], pbf[0][nt], acc);
      acc = mfma16(va[dt2][1], pbf[1][nt], acc);
      const int d0 = w * 32 + dt2 * 16 + g * 4;
      const int off = (q * 256 + d0 * 2) ^ ((q & 7) << 4);
      union { int i[2]; bf16x4 v; } u;
      u.i[0] = pk2(acc[0] * rv, acc[1] * rv);
      u.i[1] = pk2(acc[2] * rv, acc[3] * rv);
      *(bf16x4*)(smem + off) = u.v;
    }
  }

  __syncthreads();   // the ONLY barrier: O visible to all waves

  // ---- MLP on token tile w
  bf16x8 ob[4];
  {
    const int t = w * 16 + c;
#pragma unroll
    for (int kt = 0; kt < 4; ++kt) {
      const int off = (t * 256 + kt * 64 + g * 16) ^ ((t & 7) << 4);
      ob[kt] = *(const bf16x8*)(smem + off);
    }
  }
  // fc1 swapped: D[h][t] C-frags (ht 0,1); gelu; -> pairs -> ha A-frag
  int hpA[2], hpB[2];
#pragma unroll
  for (int ht = 0; ht < 2; ++ht) {
    f32x4 ah = *(const f32x4*)(f1b + ht * 16 + g * 4);
#pragma unroll
    for (int kt = 0; kt < 4; ++kt)
      ah = mfma16(f1p[(kt * 2 + ht) * 64 + l], ob[kt], ah);
    float gv[4];
#pragma unroll
    for (int r = 0; r < 4; ++r) {
      const float v = ah[r];
      gv[r] = 0.5f * v * (1.0f + erff(v * 0.70710678118654752f));
    }
    hpA[ht] = pk2(gv[0], gv[1]);
    hpB[ht] = pk2(gv[2], gv[3]);
  }
  const bf16x8 ha = xform(aA, aB, lolane, hpA[0], hpB[0], hpA[1], hpB[1]);

  // fc2 direct: D[t][d] + f2b -> global
  {
    float* og = out + b * 8192 + (size_t)(w * 16) * 128;
#pragma unroll
    for (int dt = 0; dt < 8; ++dt) {
      const float bb = f2b[dt * 16 + c];
      f32x4 ay = { bb, bb, bb, bb };
      ay = mfma16(ha, f2p[dt * 64 + l], ay);
#pragma unroll
      for (int r = 0; r < 4; ++r)
        og[(g * 4 + r) * 128 + dt * 16 + c] = ay[r];
    }
  }
}

extern "C" void kernel_launch(void* const* d_in, const int* in_sizes, int n_in,
                              void* d_out, int out_size, void* d_ws, size_t ws_size,
                              hipStream_t stream) {
  const float* x    = (const float*)d_in[0];
  const float* rpb  = (const float*)d_in[1];
  const float* wq   = (const float*)d_in[2];
  const float* bq   = (const float*)d_in[3];
  const float* wkv  = (const float*)d_in[4];
  const float* bkv  = (const float*)d_in[5];
  const float* f1w  = (const float*)d_in[6];
  const float* f1b  = (const float*)d_in[7];
  const float* f2w  = (const float*)d_in[8];
  const float* f2b  = (const float*)d_in[9];
  const int*   rel  = (const int*)d_in[10];
  float* out = (float*)d_out;
  char* ws = (char*)d_ws;
  if (ws_size < 180736) return;

  const int nB = in_sizes[0] / 8192;   // 16384 windows

  wattn_prep<<<45, 256, 0, stream>>>(wq, bq, wkv, f1w, f2w, rpb, rel, ws);
  wattn_main<<<nB, 256, 0, stream>>>(x, bkv, f1b, f2b, ws, out);
}